// Round 7
// baseline (2622.795 us; speedup 1.0000x reference)
//
#include <hip/hip_runtime.h>

// Problem constants (T,B,C,H,W = 8,32,128,32,32)
#define TT 8
#define BB 32
#define CC 128
#define HH 32
#define WW 32
#define HW 1024
#define CHW (CC*HW)             // 131072 elems per image
#define NPLANES (TT*BB)         // 256 images
#define SITES (BB*CC*HW)        // 4194304 per timestep
#define TBHW (TT*BB*HH*WW)      // 262144 per channel (BN count)
#define NCLASS 10
#define NCELL 1156              // 34*34 tile cells

typedef __attribute__((ext_vector_type(8))) short bf16x8;
typedef __attribute__((ext_vector_type(4))) float f32x4;
typedef unsigned short u16;
typedef unsigned int u32;

static __device__ __forceinline__ u16 f2bf(float f) {   // RNE fp32->bf16 (finite)
    u32 u = __builtin_bit_cast(u32, f);
    u += 0x7FFFu + ((u >> 16) & 1u);
    return (u16)(u >> 16);
}
static __device__ __forceinline__ float bf2f(u16 h) {
    return __builtin_bit_cast(float, ((u32)h) << 16);
}

// ---------------------------------------------------------------------------
// Weight prep (unchanged, verified): w[oc][ci][3][3] fp32 -> hi/lo bf16
// A-fragment tiles. Tile t = (cic*9+tap)*16 + ocg*2 + hl, 64 lanes x 16B.
// oc = ocg*16 + lane%16 (A row), ci = cic*32 + (lane>>4)*8 + j (A k).
// ---------------------------------------------------------------------------
__global__ __launch_bounds__(256) void prep_w(const float* __restrict__ w,
                                              u16* __restrict__ wA) {
    const int p = blockIdx.x * 256 + threadIdx.x;      // 0..147455
    const int off = p & 255, lane = off >> 2, jp = off & 3;
    const int tile = p >> 8;
    const int hl = tile & 1, ocg = (tile >> 1) & 7, tt = tile >> 4;
    const int tap = tt % 9, cic = tt / 9;
    const int oc = ocg * 16 + (lane & 15);
    const int cib = cic * 32 + (lane >> 4) * 8 + jp * 2;
#pragma unroll
    for (int e = 0; e < 2; ++e) {
        const float f = w[((size_t)oc * CC + cib + e) * 9 + tap];
        const u16 h = f2bf(f);
        wA[(size_t)p * 2 + e] = (hl == 0) ? h : f2bf(f - bf2f(h));
    }
}

// ---------------------------------------------------------------------------
// MFMA conv 3x3 (pad 1) + fused BN partial stats — full-image tiling.
// Block 256 thr = 4 waves = image n x 32 oc (ocset). Wave wv: rows
// [wv*8, wv*8+8) = 256 px = 16 nf-groups; acc[2 ocg][16 nf] = 128 VGPRs.
// Per (cic,tap): only 4 weight-fragment global loads feed 64 MFMAs (16:1) —
// the 9-tap unroll pipelines next-tap loads under current MFMAs.
// LDS: ONE static 74 KB tile [cell=34x34][ci 32] bf16 with octet swizzle
// slot = kk ^ (cell&3): staging b128-writes spread 32-way -> 8-way (b128
// floor); reads unchanged at 8-way. 2 blocks/CU resident.
// SPLIT (L1, fp32 input): 8 virtual chunks — vc 0..3 stage x_hi (w_hi+w_lo
// passes), vc 4..7 re-stage x_lo (w_hi pass only). Same 74 KB LDS as L2/L3.
// Grid id = (n>>3)*32 + ocset*8 + (n&7): all 4 ocset-blocks of image n are
// dispatch-adjacent on XCD n%8 (L2 shares the image + weights).
// Fragment maps (HW-verified D per m89; A/B contiguous-K per m92/m97):
//   A[row=lane%16][k=(lane>>4)*8+j], B[k=(lane>>4)*8+j][col=lane%16],
//   D[col=lane&15][row=(lane>>4)*4+reg].
// ---------------------------------------------------------------------------
template <bool SPLIT>
__global__ __launch_bounds__(256) void conv_mfma(const void* __restrict__ xin_,
                                                 const u16* __restrict__ wA,
                                                 float* __restrict__ y,
                                                 float* __restrict__ pstats) {
    __shared__ u16 xT[NCELL * 32];    // 73984 B
    const int tid = threadIdx.x;
    const int id  = blockIdx.x;
    const int ocset = (id >> 3) & 3;
    const int n     = ((id >> 5) << 3) | (id & 7);
    const int lane = tid & 63, wv = tid >> 6, kg = lane >> 4, l16 = lane & 15;

    f32x4 acc[2][16];
#pragma unroll
    for (int g = 0; g < 2; ++g)
#pragma unroll
        for (int nf = 0; nf < 16; ++nf) acc[g][nf] = (f32x4){0.f, 0.f, 0.f, 0.f};

    const int base_cl = wv * 272 + l16;   // wv*8 rows * 34 + l16

    const float* xf = (const float*)xin_;
    const u16*   xb = (const u16*)xin_;
    const bf16x8* wAv = (const bf16x8*)wA;

    const int NV = SPLIT ? 8 : 4;
    for (int vc = 0; vc < NV; ++vc) {
        const int cic = vc & 3;
        const bool lovar = SPLIT && (vc >> 2);
        __syncthreads();
        // ---- stage 32 ci x 34x34 cells (zero halo) ----
        for (int it = tid; it < 4624; it += 256) {
            const int kk = it / NCELL;             // octet 0..3 (wave-uniform-ish)
            const int cell = it - kk * NCELL;      // adjacent lanes -> adjacent cells
            const int trow = cell / 34, tcol = cell - trow * 34;
            const int grow = trow - 1, gcol = tcol - 1;
            const bool ok = ((unsigned)grow < 32u) && ((unsigned)gcol < 32u);
            u16 hh[8];
#pragma unroll
            for (int i = 0; i < 8; ++i) {
                const int ci = cic * 32 + kk * 8 + i;
                if (SPLIT) {
                    const float v = ok ? xf[(size_t)(n * CC + ci) * HW + grow * WW + gcol] : 0.0f;
                    const u16 h = f2bf(v);
                    hh[i] = lovar ? f2bf(v - bf2f(h)) : h;
                } else {
                    hh[i] = ok ? xb[(size_t)(n * CC + ci) * HW + grow * WW + gcol] : (u16)0;
                }
            }
            const int o = cell * 32 + ((kk ^ (cell & 3)) * 8);   // octet swizzle
            *(int4*)(xT + o) = make_int4((int)((u32)hh[0] | ((u32)hh[1] << 16)),
                                         (int)((u32)hh[2] | ((u32)hh[3] << 16)),
                                         (int)((u32)hh[4] | ((u32)hh[5] << 16)),
                                         (int)((u32)hh[6] | ((u32)hh[7] << 16)));
        }
        __syncthreads();
        // ---- compute: 9 taps; 4 A-loads : 64 MFMA per tap ----
#pragma unroll
        for (int tap = 0; tap < 9; ++tap) {
            const int dy = tap / 3, dx = tap % 3;
            bf16x8 ah[2], al[2];
#pragma unroll
            for (int g = 0; g < 2; ++g) {
                const int tb = (cic * 9 + tap) * 16 + (ocset * 2 + g) * 2;
                ah[g] = wAv[tb * 64 + lane];
                if (!lovar) al[g] = wAv[(tb + 1) * 64 + lane];
            }
#pragma unroll
            for (int nf = 0; nf < 16; ++nf) {
                const int cell = base_cl + (nf >> 1) * 34 + (nf & 1) * 16 + dy * 34 + dx;
                const int o = cell * 32 + ((kg ^ (cell & 3)) * 8);
                const bf16x8 b = *(const bf16x8*)(xT + o);
#pragma unroll
                for (int g = 0; g < 2; ++g)
                    acc[g][nf] = __builtin_amdgcn_mfma_f32_16x16x32_bf16(ah[g], b, acc[g][nf], 0, 0, 0);
                if (!lovar)
#pragma unroll
                    for (int g = 0; g < 2; ++g)
                        acc[g][nf] = __builtin_amdgcn_mfma_f32_16x16x32_bf16(al[g], b, acc[g][nf], 0, 0, 0);
            }
        }
    }

    // ---- store y (fp32). D: col(px)=l16, row(oc-in-16)=kg*4+reg ----
    float* yim = y + (size_t)n * CHW;
#pragma unroll
    for (int g = 0; g < 2; ++g)
#pragma unroll
        for (int r = 0; r < 4; ++r) {
            const int oc = ocset * 32 + g * 16 + kg * 4 + r;
#pragma unroll
            for (int nf = 0; nf < 16; ++nf) {
                const int row = wv * 8 + (nf >> 1), col = (nf & 1) * 16 + l16;
                yim[(size_t)oc * HW + row * WW + col] = acc[g][nf][r];
            }
        }

    // ---- fused BN partial stats: this block covers ALL px of n for 32 oc ----
    __syncthreads();                       // LDS reads done -> reuse xT
    float* sred = (float*)xT;              // [wv][st][32 oc_in] = 1 KB
#pragma unroll
    for (int g = 0; g < 2; ++g)
#pragma unroll
        for (int r = 0; r < 4; ++r) {
            float s = 0.f, s2 = 0.f;
#pragma unroll
            for (int nf = 0; nf < 16; ++nf) {
                const float v = acc[g][nf][r];
                s += v; s2 = fmaf(v, v, s2);
            }
            s  += __shfl_xor(s, 1);  s  += __shfl_xor(s, 2);
            s  += __shfl_xor(s, 4);  s  += __shfl_xor(s, 8);
            s2 += __shfl_xor(s2, 1); s2 += __shfl_xor(s2, 2);
            s2 += __shfl_xor(s2, 4); s2 += __shfl_xor(s2, 8);
            if (l16 == 0) {
                const int oc_in = g * 16 + kg * 4 + r;
                sred[wv * 64 + oc_in]      = s;
                sred[wv * 64 + 32 + oc_in] = s2;
            }
        }
    __syncthreads();
    if (tid < 64)
        pstats[(size_t)id * 64 + tid] =
            sred[tid] + sred[64 + tid] + sred[128 + tid] + sred[192 + tid];
}

// Reduce 256 per-image partials per channel -> affine (scale, shift)
__global__ void finalize_kernel(const float* __restrict__ pstats,
                                const float* __restrict__ bn_w,
                                const float* __restrict__ bn_b,
                                float* __restrict__ ss) {
    const int c = threadIdx.x;
    if (c < CC) {
        const int ocset = c >> 5, oc_in = c & 31;
        float s = 0.f, s2 = 0.f;
        for (int n = 0; n < NPLANES; ++n) {
            const int id = ((n >> 3) << 5) + ocset * 8 + (n & 7);
            s  += pstats[(size_t)id * 64 + oc_in];
            s2 += pstats[(size_t)id * 64 + 32 + oc_in];
        }
        const float inv_n = 1.0f / (float)TBHW;
        const float mean  = s * inv_n;
        const float var   = s2 * inv_n - mean * mean;   // biased var
        const float scale = bn_w[c] * rsqrtf(var + 1e-5f);
        ss[c]      = scale;
        ss[CC + c] = bn_b[c] - mean * scale;
    }
}

// ---------------------------------------------------------------------------
// Fused BN-apply + LIF. Reads fp32 conv out; writes bf16 spikes (exact {0,1}).
// POOL (last layer): skip spike store, accumulate pooled count per (b,c).
// ---------------------------------------------------------------------------
template <bool POOL>
__global__ __launch_bounds__(256) void bn_lif_kernel(const float* __restrict__ y,
                                                     const float* __restrict__ ss,
                                                     u16* __restrict__ spk,
                                                     float* __restrict__ pooled) {
    const size_t s0 = (size_t)blockIdx.x * 256 + threadIdx.x;
    const int c = (int)((s0 >> 10) & (CC - 1));
    const float scale = ss[c], shift = ss[CC + c];
    float mem = 0.f, sv = 0.f, cnt = 0.f;
#pragma unroll
    for (int t = 0; t < TT; ++t) {
        const size_t idx = (size_t)t * SITES + s0;
        const float xv = y[idx] * scale + shift;
        mem = mem * (0.25f * (1.0f - sv)) + xv;
        sv  = (mem > 0.5f) ? 1.0f : 0.0f;
        if (!POOL) spk[idx] = (mem > 0.5f) ? (u16)0x3F80 : (u16)0;
        if (POOL) cnt += sv;
    }
    if (POOL) {
#pragma unroll
        for (int off = 32; off > 0; off >>= 1) cnt += __shfl_down(cnt, off);
        __shared__ float red[4];
        if ((threadIdx.x & 63) == 0) red[threadIdx.x >> 6] = cnt;
        __syncthreads();
        if (threadIdx.x == 0) {
            const int bc = (int)(s0 >> 10);
            atomicAdd(&pooled[bc], red[0] + red[1] + red[2] + red[3]);
        }
    }
}

__global__ void fc_kernel(const float* __restrict__ pooled,
                          const float* __restrict__ fc_w,
                          const float* __restrict__ fc_b,
                          float* __restrict__ out) {
    const int i = blockIdx.x * blockDim.x + threadIdx.x;
    if (i < BB * NCLASS) {
        const int b = i / NCLASS, k = i % NCLASS;
        float acc = 0.f;
        const float inv = 1.0f / (float)(TT * HW);
        for (int c = 0; c < CC; ++c)
            acc = fmaf(pooled[b * CC + c] * inv, fc_w[k * CC + c], acc);
        out[i] = acc + fc_b[k];
    }
}

extern "C" void kernel_launch(void* const* d_in, const int* in_sizes, int n_in,
                              void* d_out, int out_size, void* d_ws, size_t ws_size,
                              hipStream_t stream) {
    const float* inp    = (const float*)d_in[0];
    const float* cw[3]  = {(const float*)d_in[1], (const float*)d_in[2], (const float*)d_in[3]};
    const float* bnw[3] = {(const float*)d_in[4], (const float*)d_in[6], (const float*)d_in[8]};
    const float* bnb[3] = {(const float*)d_in[5], (const float*)d_in[7], (const float*)d_in[9]};
    const float* fcw    = (const float*)d_in[10];
    const float* fcb    = (const float*)d_in[11];
    float* out = (float*)d_out;

    // ws layout (~203 MB): y fp32 134.2MB | spikes bf16 67.1MB | wA 0.59MB |
    // pstats 256KB | ss | pooled
    char* ws = (char*)d_ws;
    float* bufY   = (float*)ws;
    u16*   bufS   = (u16*)(ws + (size_t)TT * SITES * 4);
    u16*   wA     = (u16*)(ws + (size_t)TT * SITES * 4 + (size_t)TT * SITES * 2);
    float* pstats = (float*)((char*)wA + 589824);
    float* ss     = pstats + 1024 * 64;
    float* pooled = ss + 2 * CC;

    const void* x = (const void*)inp;
    for (int L = 0; L < 3; ++L) {
        prep_w<<<576, 256, 0, stream>>>(cw[L], wA);
        if (L == 0)
            conv_mfma<true><<<1024, 256, 0, stream>>>(x, wA, bufY, pstats);
        else
            conv_mfma<false><<<1024, 256, 0, stream>>>(x, wA, bufY, pstats);
        finalize_kernel<<<1, 128, 0, stream>>>(pstats, bnw[L], bnb[L], ss);
        if (L == 2) {
            hipMemsetAsync(pooled, 0, BB * CC * sizeof(float), stream);
            bn_lif_kernel<true><<<SITES / 256, 256, 0, stream>>>(bufY, ss, nullptr, pooled);
        } else {
            bn_lif_kernel<false><<<SITES / 256, 256, 0, stream>>>(bufY, ss, bufS, nullptr);
        }
        x = (const void*)bufS;
    }
    fc_kernel<<<5, 64, 0, stream>>>(pooled, fcw, fcb, out);
}

// Round 8
// 1136.519 us; speedup vs baseline: 2.3077x; 2.3077x over previous
//
#include <hip/hip_runtime.h>

// Problem constants (T,B,C,H,W = 8,32,128,32,32)
#define TT 8
#define BB 32
#define CC 128
#define HH 32
#define WW 32
#define HW 1024
#define CHW (CC*HW)             // 131072 elems per image
#define NPLANES (TT*BB)         // 256 images
#define SITES (BB*CC*HW)        // 4194304 per timestep
#define TBHW (TT*BB*HH*WW)      // 262144 per channel (BN count)
#define NCLASS 10

typedef __attribute__((ext_vector_type(8))) short bf16x8;
typedef __attribute__((ext_vector_type(4))) float f32x4;
typedef unsigned short u16;
typedef unsigned int u32;

static __device__ __forceinline__ u16 f2bf(float f) {   // RNE fp32->bf16 (finite)
    u32 u = __builtin_bit_cast(u32, f);
    u += 0x7FFFu + ((u >> 16) & 1u);
    return (u16)(u >> 16);
}
static __device__ __forceinline__ float bf2f(u16 h) {
    return __builtin_bit_cast(float, ((u32)h) << 16);
}

// ---------------------------------------------------------------------------
// Weight prep (verified): w[oc][ci][3][3] fp32 -> hi/lo bf16 A-fragment tiles.
// Tile t = (cic*9+tap)*16 + ocg*2 + hl, 64 lanes x 16B.
// oc = ocg*16 + lane%16 (A row), ci = cic*32 + (lane>>4)*8 + j (A k).
// ---------------------------------------------------------------------------
__global__ __launch_bounds__(256) void prep_w(const float* __restrict__ w,
                                              u16* __restrict__ wA) {
    const int p = blockIdx.x * 256 + threadIdx.x;      // 0..147455
    const int off = p & 255, lane = off >> 2, jp = off & 3;
    const int tile = p >> 8;
    const int hl = tile & 1, ocg = (tile >> 1) & 7, tt = tile >> 4;
    const int tap = tt % 9, cic = tt / 9;
    const int oc = ocg * 16 + (lane & 15);
    const int cib = cic * 32 + (lane >> 4) * 8 + jp * 2;
#pragma unroll
    for (int e = 0; e < 2; ++e) {
        const float f = w[((size_t)oc * CC + cib + e) * 9 + tap];
        const u16 h = f2bf(f);
        wA[(size_t)p * 2 + e] = (hl == 0) ? h : f2bf(f - bf2f(h));
    }
}

// ---------------------------------------------------------------------------
// MFMA conv 3x3 (pad 1) + fused BN partial stats — round-5 geometry (337 µs
// measured) + tap-level software pipeline.
// Block 256 thr = 4 waves; tile: image n, ALL 128 oc, 256 px (8 rows, qtr q).
// Wave wv: px [wv*64, wv*64+64); acc[8 ocg][4 nf] f32x4 = 128 VGPRs.
// LDS X tile: [10 rows][34 cols][ci 32, pad->40] bf16 (cell stride 80B).
// PIPELINE (the fix for MfmaUtil 29%->5% regression analysis): per (cic,tap)
// all 16 weight A-frag global loads and all 4/8 B-frag ds_reads are batched
// into double-buffered register arrays indexed by tap&1 (compile-time after
// full unroll -> stays in registers). Tap t's 64-96 back-to-back MFMAs cover
// tap t+1's load latency. Accumulation order per acc chain is IDENTICAL to
// the round-5 kernel -> bitwise-same results.
// SPLIT=true (L1, fp32 input): hi+lo X tiles staged, 3 passes per tap
// (w_hi*x_hi + w_lo*x_hi + w_hi*x_lo). SPLIT=false: {0,1} bf16 spikes, 2.
// Grid id = q*256 + n -> all 4 quarters of image n on XCD n%8.
// Fragment maps (HW-verified D per m89; A/B contiguous-K per m92/m97):
//   A[row=lane%16][k=(lane>>4)*8+j], B[k=(lane>>4)*8+j][col=lane%16],
//   D[col=lane&15][row=(lane>>4)*4+reg].
// ---------------------------------------------------------------------------
template <bool SPLIT>
__global__ __launch_bounds__(256) void conv_mfma(const void* __restrict__ xin_,
                                                 const u16* __restrict__ wA,
                                                 float* __restrict__ y,
                                                 float* __restrict__ pstats) {
    extern __shared__ u16 smem[];
    u16* hiT = smem;                  // [10][34][40] = 13600 u16 = 27.2KB
    u16* loT = smem + 13600;          // SPLIT only
    const int tid = threadIdx.x;
    const int id  = blockIdx.x;
    const int n   = id & 255, q = id >> 8;
    const int lane = tid & 63, wv = tid >> 6, kg = lane >> 4, l16 = lane & 15;

    f32x4 acc[8][4];
#pragma unroll
    for (int g = 0; g < 8; ++g)
#pragma unroll
        for (int nf = 0; nf < 4; ++nf) acc[g][nf] = (f32x4){0.f, 0.f, 0.f, 0.f};

    int off0[4];                      // u16 offset of tap(0,0) B-frag per nf
#pragma unroll
    for (int nf = 0; nf < 4; ++nf) {
        const int px = wv * 64 + nf * 16 + l16;
        off0[nf] = ((px >> 5) * 34 + (px & 31)) * 40 + kg * 8;
    }

    const float* xf = (const float*)xin_;
    const u16*   xb = (const u16*)xin_;
    const bf16x8* wAv = (const bf16x8*)wA;

    for (int cic = 0; cic < 4; ++cic) {
        __syncthreads();
        // ---- stage 32 ci x 10 rows x 34 cols (zero halo) ----
        for (int it = tid; it < 1360; it += 256) {
            const int kk = it / 340, cell = it - kk * 340;
            const int trow = cell / 34, tcol = cell - trow * 34;
            const int grow = q * 8 - 1 + trow, gcol = tcol - 1;
            const bool ok = ((unsigned)grow < 32u) && ((unsigned)gcol < 32u);
            u16 hh[8], ll[8];
#pragma unroll
            for (int i = 0; i < 8; ++i) {
                const int ci = cic * 32 + kk * 8 + i;
                if (SPLIT) {
                    const float v = ok ? xf[(size_t)(n * CC + ci) * HW + grow * WW + gcol] : 0.0f;
                    const u16 h = f2bf(v);
                    hh[i] = h;
                    ll[i] = f2bf(v - bf2f(h));
                } else {
                    hh[i] = ok ? xb[(size_t)(n * CC + ci) * HW + grow * WW + gcol] : (u16)0;
                }
            }
            const int o = cell * 40 + kk * 8;
            *(int4*)(hiT + o) = make_int4((int)((u32)hh[0] | ((u32)hh[1] << 16)),
                                          (int)((u32)hh[2] | ((u32)hh[3] << 16)),
                                          (int)((u32)hh[4] | ((u32)hh[5] << 16)),
                                          (int)((u32)hh[6] | ((u32)hh[7] << 16)));
            if (SPLIT)
                *(int4*)(loT + o) = make_int4((int)((u32)ll[0] | ((u32)ll[1] << 16)),
                                              (int)((u32)ll[2] | ((u32)ll[3] << 16)),
                                              (int)((u32)ll[4] | ((u32)ll[5] << 16)),
                                              (int)((u32)ll[6] | ((u32)ll[7] << 16)));
        }
        __syncthreads();

        // ---- software-pipelined compute: 9 taps ----
        bf16x8 ahb[2][8], alb[2][8], bhb[2][4], blb[2][4];
        {   // prologue: tap 0 inputs (dy=0, dx=0 -> delta 0)
            const int tb0 = (cic * 9) * 16;
#pragma unroll
            for (int g = 0; g < 8; ++g) {
                ahb[0][g] = wAv[(tb0 + g * 2) * 64 + lane];
                alb[0][g] = wAv[(tb0 + g * 2 + 1) * 64 + lane];
            }
#pragma unroll
            for (int nf = 0; nf < 4; ++nf) {
                bhb[0][nf] = *(const bf16x8*)(hiT + off0[nf]);
                if (SPLIT) blb[0][nf] = *(const bf16x8*)(loT + off0[nf]);
            }
        }
#pragma unroll
        for (int tap = 0; tap < 9; ++tap) {
            const int cur = tap & 1, nxt = cur ^ 1;
            if (tap < 8) {            // prefetch tap+1 inputs (compile-time)
                const int tap1 = tap + 1;
                const int dd = ((tap1 / 3) * 34 + (tap1 % 3)) * 40;
                const int tb1 = (cic * 9 + tap1) * 16;
#pragma unroll
                for (int g = 0; g < 8; ++g) {
                    ahb[nxt][g] = wAv[(tb1 + g * 2) * 64 + lane];
                    alb[nxt][g] = wAv[(tb1 + g * 2 + 1) * 64 + lane];
                }
#pragma unroll
                for (int nf = 0; nf < 4; ++nf) {
                    bhb[nxt][nf] = *(const bf16x8*)(hiT + off0[nf] + dd);
                    if (SPLIT) blb[nxt][nf] = *(const bf16x8*)(loT + off0[nf] + dd);
                }
            }
            // 64-96 back-to-back MFMAs; same acc-chain order as round-5
#pragma unroll
            for (int nf = 0; nf < 4; ++nf) {
#pragma unroll
                for (int g = 0; g < 8; ++g)
                    acc[g][nf] = __builtin_amdgcn_mfma_f32_16x16x32_bf16(ahb[cur][g], bhb[cur][nf], acc[g][nf], 0, 0, 0);
#pragma unroll
                for (int g = 0; g < 8; ++g)
                    acc[g][nf] = __builtin_amdgcn_mfma_f32_16x16x32_bf16(alb[cur][g], bhb[cur][nf], acc[g][nf], 0, 0, 0);
                if (SPLIT) {
#pragma unroll
                    for (int g = 0; g < 8; ++g)
                        acc[g][nf] = __builtin_amdgcn_mfma_f32_16x16x32_bf16(ahb[cur][g], blb[cur][nf], acc[g][nf], 0, 0, 0);
                }
            }
        }
    }

    // ---- store y (fp32). D map: col(px)=lane&15, row(oc)=(lane>>4)*4+reg ----
    float* yp = y + (size_t)n * CHW + q * 256;
#pragma unroll
    for (int g = 0; g < 8; ++g)
#pragma unroll
        for (int r = 0; r < 4; ++r) {
            const int oc = g * 16 + kg * 4 + r;
#pragma unroll
            for (int nf = 0; nf < 4; ++nf)
                yp[(size_t)oc * HW + wv * 64 + nf * 16 + l16] = acc[g][nf][r];
        }

    // ---- fused BN partial stats over this block's 256 px, all 128 oc ----
    __syncthreads();                       // all LDS compute reads done -> reuse smem
    float* sred = (float*)smem;            // [4 waves][128 oc][2] = 4KB
#pragma unroll
    for (int g = 0; g < 8; ++g)
#pragma unroll
        for (int r = 0; r < 4; ++r) {
            float s = 0.f, s2 = 0.f;
#pragma unroll
            for (int nf = 0; nf < 4; ++nf) {
                const float v = acc[g][nf][r];
                s += v; s2 = fmaf(v, v, s2);
            }
            s  += __shfl_xor(s, 1);  s  += __shfl_xor(s, 2);
            s  += __shfl_xor(s, 4);  s  += __shfl_xor(s, 8);
            s2 += __shfl_xor(s2, 1); s2 += __shfl_xor(s2, 2);
            s2 += __shfl_xor(s2, 4); s2 += __shfl_xor(s2, 8);
            if (l16 == 0) {
                const int oc = g * 16 + kg * 4 + r;
                sred[(wv * 128 + oc) * 2 + 0] = s;
                sred[(wv * 128 + oc) * 2 + 1] = s2;
            }
        }
    __syncthreads();
    if (tid < 128) {
        float s = 0.f, s2 = 0.f;
#pragma unroll
        for (int w2 = 0; w2 < 4; ++w2) {
            s  += sred[(w2 * 128 + tid) * 2 + 0];
            s2 += sred[(w2 * 128 + tid) * 2 + 1];
        }
        pstats[(size_t)id * 256 + tid]       = s;
        pstats[(size_t)id * 256 + 128 + tid] = s2;
    }
}

// Reduce 1024 per-block partials per channel -> affine (scale, shift)
__global__ void finalize_kernel(const float* __restrict__ pstats,
                                const float* __restrict__ bn_w,
                                const float* __restrict__ bn_b,
                                float* __restrict__ ss) {
    const int c = threadIdx.x;
    if (c < CC) {
        float s = 0.f, s2 = 0.f;
        for (int i = 0; i < 1024; ++i) {
            s  += pstats[(size_t)i * 256 + c];
            s2 += pstats[(size_t)i * 256 + 128 + c];
        }
        const float inv_n = 1.0f / (float)TBHW;
        const float mean  = s * inv_n;
        const float var   = s2 * inv_n - mean * mean;   // biased var
        const float scale = bn_w[c] * rsqrtf(var + 1e-5f);
        ss[c]      = scale;
        ss[CC + c] = bn_b[c] - mean * scale;
    }
}

// ---------------------------------------------------------------------------
// Fused BN-apply + LIF. Reads fp32 conv out; writes bf16 spikes (exact {0,1}).
// POOL (last layer): skip spike store, accumulate pooled count per (b,c).
// ---------------------------------------------------------------------------
template <bool POOL>
__global__ __launch_bounds__(256) void bn_lif_kernel(const float* __restrict__ y,
                                                     const float* __restrict__ ss,
                                                     u16* __restrict__ spk,
                                                     float* __restrict__ pooled) {
    const size_t s0 = (size_t)blockIdx.x * 256 + threadIdx.x;
    const int c = (int)((s0 >> 10) & (CC - 1));
    const float scale = ss[c], shift = ss[CC + c];
    float mem = 0.f, sv = 0.f, cnt = 0.f;
#pragma unroll
    for (int t = 0; t < TT; ++t) {
        const size_t idx = (size_t)t * SITES + s0;
        const float xv = y[idx] * scale + shift;
        mem = mem * (0.25f * (1.0f - sv)) + xv;
        sv  = (mem > 0.5f) ? 1.0f : 0.0f;
        if (!POOL) spk[idx] = (mem > 0.5f) ? (u16)0x3F80 : (u16)0;
        if (POOL) cnt += sv;
    }
    if (POOL) {
#pragma unroll
        for (int off = 32; off > 0; off >>= 1) cnt += __shfl_down(cnt, off);
        __shared__ float red[4];
        if ((threadIdx.x & 63) == 0) red[threadIdx.x >> 6] = cnt;
        __syncthreads();
        if (threadIdx.x == 0) {
            const int bc = (int)(s0 >> 10);
            atomicAdd(&pooled[bc], red[0] + red[1] + red[2] + red[3]);
        }
    }
}

__global__ void fc_kernel(const float* __restrict__ pooled,
                          const float* __restrict__ fc_w,
                          const float* __restrict__ fc_b,
                          float* __restrict__ out) {
    const int i = blockIdx.x * blockDim.x + threadIdx.x;
    if (i < BB * NCLASS) {
        const int b = i / NCLASS, k = i % NCLASS;
        float acc = 0.f;
        const float inv = 1.0f / (float)(TT * HW);
        for (int c = 0; c < CC; ++c)
            acc = fmaf(pooled[b * CC + c] * inv, fc_w[k * CC + c], acc);
        out[i] = acc + fc_b[k];
    }
}

extern "C" void kernel_launch(void* const* d_in, const int* in_sizes, int n_in,
                              void* d_out, int out_size, void* d_ws, size_t ws_size,
                              hipStream_t stream) {
    const float* inp    = (const float*)d_in[0];
    const float* cw[3]  = {(const float*)d_in[1], (const float*)d_in[2], (const float*)d_in[3]};
    const float* bnw[3] = {(const float*)d_in[4], (const float*)d_in[6], (const float*)d_in[8]};
    const float* bnb[3] = {(const float*)d_in[5], (const float*)d_in[7], (const float*)d_in[9]};
    const float* fcw    = (const float*)d_in[10];
    const float* fcb    = (const float*)d_in[11];
    float* out = (float*)d_out;

    // ws layout (~203 MB): y fp32 134.2MB | spikes bf16 67.1MB | wA 0.59MB |
    // pstats 1MB | ss | pooled
    char* ws = (char*)d_ws;
    float* bufY   = (float*)ws;
    u16*   bufS   = (u16*)(ws + (size_t)TT * SITES * 4);
    u16*   wA     = (u16*)(ws + (size_t)TT * SITES * 4 + (size_t)TT * SITES * 2);
    float* pstats = (float*)((char*)wA + 589824);
    float* ss     = pstats + 1024 * 256;
    float* pooled = ss + 2 * CC;

    const void* x = (const void*)inp;
    for (int L = 0; L < 3; ++L) {
        prep_w<<<576, 256, 0, stream>>>(cw[L], wA);
        if (L == 0)
            conv_mfma<true><<<1024, 256, 2 * 13600 * sizeof(u16), stream>>>(x, wA, bufY, pstats);
        else
            conv_mfma<false><<<1024, 256, 13600 * sizeof(u16), stream>>>(x, wA, bufY, pstats);
        finalize_kernel<<<1, 128, 0, stream>>>(pstats, bnw[L], bnb[L], ss);
        if (L == 2) {
            hipMemsetAsync(pooled, 0, BB * CC * sizeof(float), stream);
            bn_lif_kernel<true><<<SITES / 256, 256, 0, stream>>>(bufY, ss, nullptr, pooled);
        } else {
            bn_lif_kernel<false><<<SITES / 256, 256, 0, stream>>>(bufY, ss, bufS, nullptr);
        }
        x = (const void*)bufS;
    }
    fc_kernel<<<5, 64, 0, stream>>>(pooled, fcw, fcb, out);
}

// Round 9
// 860.435 us; speedup vs baseline: 3.0482x; 1.3209x over previous
//
#include <hip/hip_runtime.h>

// Problem constants (T,B,C,H,W = 8,32,128,32,32)
#define TT 8
#define BB 32
#define CC 128
#define HH 32
#define WW 32
#define HW 1024
#define CHW (CC*HW)             // 131072 elems per image
#define NPLANES (TT*BB)         // 256 images
#define SITES (BB*CC*HW)        // 4194304 per timestep
#define TBHW (TT*BB*HH*WW)      // 262144 per channel (BN count)
#define NCLASS 10

typedef __attribute__((ext_vector_type(8))) short bf16x8;
typedef __attribute__((ext_vector_type(4))) float f32x4;
typedef unsigned short u16;
typedef unsigned int u32;

static __device__ __forceinline__ u16 f2bf(float f) {   // RNE fp32->bf16 (finite)
    u32 u = __builtin_bit_cast(u32, f);
    u += 0x7FFFu + ((u >> 16) & 1u);
    return (u16)(u >> 16);
}
static __device__ __forceinline__ float bf2f(u16 h) {
    return __builtin_bit_cast(float, ((u32)h) << 16);
}

// ---------------------------------------------------------------------------
// Weight prep (verified): w[oc][ci][3][3] fp32 -> hi/lo bf16 A-fragment tiles.
// Tile t = (cic*9+tap)*16 + ocg*2 + hl, 64 lanes x 16B.
// oc = ocg*16 + lane%16 (A row), ci = cic*32 + (lane>>4)*8 + j (A k).
// ---------------------------------------------------------------------------
__global__ __launch_bounds__(256) void prep_w(const float* __restrict__ w,
                                              u16* __restrict__ wA) {
    const int p = blockIdx.x * 256 + threadIdx.x;      // 0..147455
    const int off = p & 255, lane = off >> 2, jp = off & 3;
    const int tile = p >> 8;
    const int hl = tile & 1, ocg = (tile >> 1) & 7, tt = tile >> 4;
    const int tap = tt % 9, cic = tt / 9;
    const int oc = ocg * 16 + (lane & 15);
    const int cib = cic * 32 + (lane >> 4) * 8 + jp * 2;
#pragma unroll
    for (int e = 0; e < 2; ++e) {
        const float f = w[((size_t)oc * CC + cib + e) * 9 + tap];
        const u16 h = f2bf(f);
        wA[(size_t)p * 2 + e] = (hl == 0) ? h : f2bf(f - bf2f(h));
    }
}

// ---------------------------------------------------------------------------
// MFMA conv 3x3 (pad 1) + fused BN partial stats.
// Round-5 geometry (337 µs measured) with the per-wave footprint HALVED to
// enable 2 waves/SIMD (the round-8 post-mortem: acc128+VGPR~150 on the
// unified file = ~280 regs/wave = 1 wave/SIMD = zero latency hiding).
// Block 512 thr = 8 waves = image-quarter q of image n, ALL 128 oc.
// Wave (wo,wp): oc half wo (64 oc = 4 ocg), px quarter wp (64 px).
// acc[4 ocg][4 nf] f32x4 = 64 AGPRs; ~170 total regs -> 2 waves/SIMD.
// Per tap per wave: 8 A global loads + 4 (or 8) B ds_reads feed 32 (48) MFMAs;
// the sibling wave on the same SIMD hides the waits. Simple loop body —
// compiler schedules (explicit dbuf was neutral, round-8).
// LDS X tile: [10 rows][34 cols][ci 32, pad->40] bf16, shared by all 8 waves.
// SPLIT=true (L1, fp32 in): hi+lo tiles, 3 passes/tap. Else 2 passes.
// Accumulation-chain order per acc identical to rounds 5-8 -> bitwise-same.
// Grid id = q*256 + n -> all 4 quarters of image n on XCD n%8.
// Fragment maps (HW-verified D per m89; A/B contiguous-K per m92/m97):
//   A[row=lane%16][k=(lane>>4)*8+j], B[k=(lane>>4)*8+j][col=lane%16],
//   D[col=lane&15][row=(lane>>4)*4+reg].
// ---------------------------------------------------------------------------
template <bool SPLIT>
__global__ __launch_bounds__(512) void conv_mfma(const void* __restrict__ xin_,
                                                 const u16* __restrict__ wA,
                                                 float* __restrict__ y,
                                                 float* __restrict__ pstats) {
    extern __shared__ u16 smem[];
    u16* hiT = smem;                  // [10][34][40] = 13600 u16 = 27.2KB
    u16* loT = smem + 13600;          // SPLIT only
    const int tid = threadIdx.x;
    const int id  = blockIdx.x;
    const int n   = id & 255, q = id >> 8;
    const int lane = tid & 63, wave = tid >> 6;
    const int wo = wave >> 2, wp = wave & 3;
    const int kg = lane >> 4, l16 = lane & 15;

    f32x4 acc[4][4];
#pragma unroll
    for (int g = 0; g < 4; ++g)
#pragma unroll
        for (int nf = 0; nf < 4; ++nf) acc[g][nf] = (f32x4){0.f, 0.f, 0.f, 0.f};

    int off0[4];                      // u16 offset of tap(0,0) B-frag per nf
#pragma unroll
    for (int nf = 0; nf < 4; ++nf) {
        const int px = wp * 64 + nf * 16 + l16;
        off0[nf] = ((px >> 5) * 34 + (px & 31)) * 40 + kg * 8;
    }

    const float* xf = (const float*)xin_;
    const u16*   xb = (const u16*)xin_;
    const bf16x8* wAv = (const bf16x8*)wA;

    for (int cic = 0; cic < 4; ++cic) {
        __syncthreads();
        // ---- stage 32 ci x 10 rows x 34 cols (zero halo) ----
        for (int it = tid; it < 1360; it += 512) {
            const int kk = it / 340, cell = it - kk * 340;
            const int trow = cell / 34, tcol = cell - trow * 34;
            const int grow = q * 8 - 1 + trow, gcol = tcol - 1;
            const bool ok = ((unsigned)grow < 32u) && ((unsigned)gcol < 32u);
            u16 hh[8], ll[8];
#pragma unroll
            for (int i = 0; i < 8; ++i) {
                const int ci = cic * 32 + kk * 8 + i;
                if (SPLIT) {
                    const float v = ok ? xf[(size_t)(n * CC + ci) * HW + grow * WW + gcol] : 0.0f;
                    const u16 h = f2bf(v);
                    hh[i] = h;
                    ll[i] = f2bf(v - bf2f(h));
                } else {
                    hh[i] = ok ? xb[(size_t)(n * CC + ci) * HW + grow * WW + gcol] : (u16)0;
                }
            }
            const int o = cell * 40 + kk * 8;
            *(int4*)(hiT + o) = make_int4((int)((u32)hh[0] | ((u32)hh[1] << 16)),
                                          (int)((u32)hh[2] | ((u32)hh[3] << 16)),
                                          (int)((u32)hh[4] | ((u32)hh[5] << 16)),
                                          (int)((u32)hh[6] | ((u32)hh[7] << 16)));
            if (SPLIT)
                *(int4*)(loT + o) = make_int4((int)((u32)ll[0] | ((u32)ll[1] << 16)),
                                              (int)((u32)ll[2] | ((u32)ll[3] << 16)),
                                              (int)((u32)ll[4] | ((u32)ll[5] << 16)),
                                              (int)((u32)ll[6] | ((u32)ll[7] << 16)));
        }
        __syncthreads();

        // ---- compute: 9 taps; 8 A-loads + 4/8 B-reads : 32/48 MFMAs ----
#pragma unroll
        for (int tap = 0; tap < 9; ++tap) {
            const int dd = ((tap / 3) * 34 + (tap % 3)) * 40;
            bf16x8 ah[4], al[4];
#pragma unroll
            for (int g = 0; g < 4; ++g) {
                const int tb = (cic * 9 + tap) * 16 + (wo * 4 + g) * 2;
                ah[g] = wAv[tb * 64 + lane];
                al[g] = wAv[(tb + 1) * 64 + lane];
            }
#pragma unroll
            for (int nf = 0; nf < 4; ++nf) {
                const bf16x8 b = *(const bf16x8*)(hiT + off0[nf] + dd);
#pragma unroll
                for (int g = 0; g < 4; ++g)
                    acc[g][nf] = __builtin_amdgcn_mfma_f32_16x16x32_bf16(ah[g], b, acc[g][nf], 0, 0, 0);
#pragma unroll
                for (int g = 0; g < 4; ++g)
                    acc[g][nf] = __builtin_amdgcn_mfma_f32_16x16x32_bf16(al[g], b, acc[g][nf], 0, 0, 0);
                if (SPLIT) {
                    const bf16x8 bl = *(const bf16x8*)(loT + off0[nf] + dd);
#pragma unroll
                    for (int g = 0; g < 4; ++g)
                        acc[g][nf] = __builtin_amdgcn_mfma_f32_16x16x32_bf16(ah[g], bl, acc[g][nf], 0, 0, 0);
                }
            }
        }
    }

    // ---- store y (fp32). D map: col(px)=lane&15, row(oc)=(lane>>4)*4+reg ----
    float* yp = y + (size_t)n * CHW + q * 256;
#pragma unroll
    for (int g = 0; g < 4; ++g)
#pragma unroll
        for (int r = 0; r < 4; ++r) {
            const int oc = wo * 64 + g * 16 + kg * 4 + r;
#pragma unroll
            for (int nf = 0; nf < 4; ++nf)
                yp[(size_t)oc * HW + wp * 64 + nf * 16 + l16] = acc[g][nf][r];
        }

    // ---- fused BN partial stats over this block's 256 px, all 128 oc ----
    __syncthreads();                       // all LDS compute reads done -> reuse smem
    float* sred = (float*)smem;            // [4 wp][128 oc][2] = 4KB
#pragma unroll
    for (int g = 0; g < 4; ++g)
#pragma unroll
        for (int r = 0; r < 4; ++r) {
            float s = 0.f, s2 = 0.f;
#pragma unroll
            for (int nf = 0; nf < 4; ++nf) {
                const float v = acc[g][nf][r];
                s += v; s2 = fmaf(v, v, s2);
            }
            s  += __shfl_xor(s, 1);  s  += __shfl_xor(s, 2);
            s  += __shfl_xor(s, 4);  s  += __shfl_xor(s, 8);
            s2 += __shfl_xor(s2, 1); s2 += __shfl_xor(s2, 2);
            s2 += __shfl_xor(s2, 4); s2 += __shfl_xor(s2, 8);
            if (l16 == 0) {
                const int oc = wo * 64 + g * 16 + kg * 4 + r;
                sred[(wp * 128 + oc) * 2 + 0] = s;
                sred[(wp * 128 + oc) * 2 + 1] = s2;
            }
        }
    __syncthreads();
    if (tid < 128) {
        float s = 0.f, s2 = 0.f;
#pragma unroll
        for (int w2 = 0; w2 < 4; ++w2) {
            s  += sred[(w2 * 128 + tid) * 2 + 0];
            s2 += sred[(w2 * 128 + tid) * 2 + 1];
        }
        pstats[(size_t)id * 256 + tid]       = s;
        pstats[(size_t)id * 256 + 128 + tid] = s2;
    }
}

// Reduce 1024 per-block partials per channel -> affine (scale, shift)
__global__ void finalize_kernel(const float* __restrict__ pstats,
                                const float* __restrict__ bn_w,
                                const float* __restrict__ bn_b,
                                float* __restrict__ ss) {
    const int c = threadIdx.x;
    if (c < CC) {
        float s = 0.f, s2 = 0.f;
        for (int i = 0; i < 1024; ++i) {
            s  += pstats[(size_t)i * 256 + c];
            s2 += pstats[(size_t)i * 256 + 128 + c];
        }
        const float inv_n = 1.0f / (float)TBHW;
        const float mean  = s * inv_n;
        const float var   = s2 * inv_n - mean * mean;   // biased var
        const float scale = bn_w[c] * rsqrtf(var + 1e-5f);
        ss[c]      = scale;
        ss[CC + c] = bn_b[c] - mean * scale;
    }
}

// ---------------------------------------------------------------------------
// Fused BN-apply + LIF. Reads fp32 conv out; writes bf16 spikes (exact {0,1}).
// POOL (last layer): skip spike store, accumulate pooled count per (b,c).
// ---------------------------------------------------------------------------
template <bool POOL>
__global__ __launch_bounds__(256) void bn_lif_kernel(const float* __restrict__ y,
                                                     const float* __restrict__ ss,
                                                     u16* __restrict__ spk,
                                                     float* __restrict__ pooled) {
    const size_t s0 = (size_t)blockIdx.x * 256 + threadIdx.x;
    const int c = (int)((s0 >> 10) & (CC - 1));
    const float scale = ss[c], shift = ss[CC + c];
    float mem = 0.f, sv = 0.f, cnt = 0.f;
#pragma unroll
    for (int t = 0; t < TT; ++t) {
        const size_t idx = (size_t)t * SITES + s0;
        const float xv = y[idx] * scale + shift;
        mem = mem * (0.25f * (1.0f - sv)) + xv;
        sv  = (mem > 0.5f) ? 1.0f : 0.0f;
        if (!POOL) spk[idx] = (mem > 0.5f) ? (u16)0x3F80 : (u16)0;
        if (POOL) cnt += sv;
    }
    if (POOL) {
#pragma unroll
        for (int off = 32; off > 0; off >>= 1) cnt += __shfl_down(cnt, off);
        __shared__ float red[4];
        if ((threadIdx.x & 63) == 0) red[threadIdx.x >> 6] = cnt;
        __syncthreads();
        if (threadIdx.x == 0) {
            const int bc = (int)(s0 >> 10);
            atomicAdd(&pooled[bc], red[0] + red[1] + red[2] + red[3]);
        }
    }
}

__global__ void fc_kernel(const float* __restrict__ pooled,
                          const float* __restrict__ fc_w,
                          const float* __restrict__ fc_b,
                          float* __restrict__ out) {
    const int i = blockIdx.x * blockDim.x + threadIdx.x;
    if (i < BB * NCLASS) {
        const int b = i / NCLASS, k = i % NCLASS;
        float acc = 0.f;
        const float inv = 1.0f / (float)(TT * HW);
        for (int c = 0; c < CC; ++c)
            acc = fmaf(pooled[b * CC + c] * inv, fc_w[k * CC + c], acc);
        out[i] = acc + fc_b[k];
    }
}

extern "C" void kernel_launch(void* const* d_in, const int* in_sizes, int n_in,
                              void* d_out, int out_size, void* d_ws, size_t ws_size,
                              hipStream_t stream) {
    const float* inp    = (const float*)d_in[0];
    const float* cw[3]  = {(const float*)d_in[1], (const float*)d_in[2], (const float*)d_in[3]};
    const float* bnw[3] = {(const float*)d_in[4], (const float*)d_in[6], (const float*)d_in[8]};
    const float* bnb[3] = {(const float*)d_in[5], (const float*)d_in[7], (const float*)d_in[9]};
    const float* fcw    = (const float*)d_in[10];
    const float* fcb    = (const float*)d_in[11];
    float* out = (float*)d_out;

    // ws layout (~203 MB): y fp32 134.2MB | spikes bf16 67.1MB | wA 0.59MB |
    // pstats 1MB | ss | pooled
    char* ws = (char*)d_ws;
    float* bufY   = (float*)ws;
    u16*   bufS   = (u16*)(ws + (size_t)TT * SITES * 4);
    u16*   wA     = (u16*)(ws + (size_t)TT * SITES * 4 + (size_t)TT * SITES * 2);
    float* pstats = (float*)((char*)wA + 589824);
    float* ss     = pstats + 1024 * 256;
    float* pooled = ss + 2 * CC;

    const void* x = (const void*)inp;
    for (int L = 0; L < 3; ++L) {
        prep_w<<<576, 256, 0, stream>>>(cw[L], wA);
        if (L == 0)
            conv_mfma<true><<<1024, 512, 2 * 13600 * sizeof(u16), stream>>>(x, wA, bufY, pstats);
        else
            conv_mfma<false><<<1024, 512, 13600 * sizeof(u16), stream>>>(x, wA, bufY, pstats);
        finalize_kernel<<<1, 128, 0, stream>>>(pstats, bnw[L], bnb[L], ss);
        if (L == 2) {
            hipMemsetAsync(pooled, 0, BB * CC * sizeof(float), stream);
            bn_lif_kernel<true><<<SITES / 256, 256, 0, stream>>>(bufY, ss, nullptr, pooled);
        } else {
            bn_lif_kernel<false><<<SITES / 256, 256, 0, stream>>>(bufY, ss, bufS, nullptr);
        }
        x = (const void*)bufS;
    }
    fc_kernel<<<5, 64, 0, stream>>>(pooled, fcw, fcb, out);
}